// Round 3
// baseline (771.193 us; speedup 1.0000x reference)
//
#include <hip/hip_runtime.h>
#include <stdint.h>

#define DIM 256
#define TOPK 64
#define HIST_BINS 65536
#define CAP 4096

// Monotone float->uint mapping: a > b  <=>  fkey(a) > fkey(b)
__device__ __forceinline__ uint32_t fkey(float f) {
  uint32_t u = __float_as_uint(f);
  return (u & 0x80000000u) ? ~u : (u | 0x80000000u);
}

__device__ __forceinline__ float dot4(float4 a, float4 q) {
  return a.x * q.x + a.y * q.y + a.z * q.z + a.w * q.w;
}

// Kernel Z: zero hist + candidate counter. 64 blocks x 256 thr x 16 B = 256 KB.
__global__ __launch_bounds__(256) void zero_kernel(uint32_t* __restrict__ hist,
                                                   int* __restrict__ cnt) {
  int tid = blockIdx.x * 256 + threadIdx.x;
  ((uint4*)hist)[tid] = make_uint4(0u, 0u, 0u, 0u);
  if (tid == 0) *cnt = 0;
}

// Kernel S: scores + fused histogram.
// Each wave handles 8 contiguous rows per iteration: 16-lane group `sub` owns
// rows base+sub and base+4+sub. 8 independent float4 loads (128 B) in flight
// per thread, two independent 4-step shfl reduce chains.
// Grid is sized host-side so every wave runs the same iteration count.
__global__ __launch_bounds__(256) void score_kernel(
    const float* __restrict__ mat, const float* __restrict__ query,
    float* __restrict__ scores, uint32_t* __restrict__ hist, int n) {
  const int lane = threadIdx.x & 63;
  const int li = lane & 15;   // position within 16-lane group
  const int sub = lane >> 4;  // which of the wave's 4 row-pairs
  const int gw = blockIdx.x * 4 + (threadIdx.x >> 6);
  const int W = gridDim.x * 4;

  // query fragment for this lane's column slots (L1-resident broadcast)
  float4 q0 = ((const float4*)query)[li];
  float4 q1 = ((const float4*)query)[li + 16];
  float4 q2 = ((const float4*)query)[li + 32];
  float4 q3 = ((const float4*)query)[li + 48];

  int n8 = (n + 7) >> 3;
  for (int r8 = gw; r8 < n8; r8 += W) {
    int rowA = r8 * 8 + sub;
    int rowB = rowA + 4;
    float dA = 0.f, dB = 0.f;
    if (rowB < n) {
      const float4* mA = (const float4*)(mat + (size_t)rowA * DIM);
      const float4* mB = (const float4*)(mat + (size_t)rowB * DIM);
      float4 a0 = mA[li], a1 = mA[li + 16], a2 = mA[li + 32], a3 = mA[li + 48];
      float4 b0 = mB[li], b1 = mB[li + 16], b2 = mB[li + 32], b3 = mB[li + 48];
      dA = dot4(a0, q0) + dot4(a1, q1) + dot4(a2, q2) + dot4(a3, q3);
      dB = dot4(b0, q0) + dot4(b1, q1) + dot4(b2, q2) + dot4(b3, q3);
    } else if (rowA < n) {
      const float4* mA = (const float4*)(mat + (size_t)rowA * DIM);
      float4 a0 = mA[li], a1 = mA[li + 16], a2 = mA[li + 32], a3 = mA[li + 48];
      dA = dot4(a0, q0) + dot4(a1, q1) + dot4(a2, q2) + dot4(a3, q3);
    }
#pragma unroll
    for (int off = 8; off > 0; off >>= 1) {
      dA += __shfl_xor(dA, off, 64);
      dB += __shfl_xor(dB, off, 64);
    }
    if (li == 0) {
      if (rowA < n) {
        scores[rowA] = dA;
        atomicAdd(&hist[fkey(dA) >> 16], 1u);  // fire-and-forget
      }
      if (rowB < n) {
        scores[rowB] = dB;
        atomicAdd(&hist[fkey(dB) >> 16], 1u);
      }
    }
  }
}

// Kernel C: threshold (computed redundantly per block from the L2-resident
// histogram — removes the single-block thresh bubble) + candidate collect.
// Packed key: (monotone score << 32) | ~idx -> bigger = better, ties -> lower idx.
__global__ __launch_bounds__(256) void collect_kernel(
    const float* __restrict__ scores, const uint32_t* __restrict__ hist,
    int* __restrict__ cnt, unsigned long long* __restrict__ cand, int n) {
  __shared__ uint32_t s[256];
  __shared__ int fc;
  __shared__ uint32_t above;
  __shared__ int tb;
  int t = threadIdx.x;

  // ---- threshold: smallest bin T with suffix-count >= TOPK ----
  uint32_t acc = 0;
  const uint4* h4 = (const uint4*)(hist + t * 256);
  for (int j = 0; j < 64; ++j) {
    uint4 v = h4[j];
    acc += v.x + v.y + v.z + v.w;
  }
  s[t] = acc;
  __syncthreads();
  for (int off = 1; off < 256; off <<= 1) {
    uint32_t v = (t + off < 256) ? s[t + off] : 0u;
    __syncthreads();
    s[t] += v;
    __syncthreads();
  }
  if (s[t] >= TOPK && (t == 255 || s[t + 1] < TOPK)) {
    fc = t;
    above = (t == 255) ? 0u : s[t + 1];
  }
  __syncthreads();
  int c = fc;
  uint32_t a = above;
  uint32_t h = hist[c * 256 + t];
  __syncthreads();
  s[t] = h;
  __syncthreads();
  for (int off = 1; off < 256; off <<= 1) {
    uint32_t v = (t + off < 256) ? s[t + off] : 0u;
    __syncthreads();
    s[t] += v;
    __syncthreads();
  }
  if (a + s[t] >= TOPK && (t == 255 || a + s[t + 1] < TOPK)) {
    tb = c * 256 + t;
  }
  __syncthreads();
  uint32_t T = (uint32_t)tb;

  // ---- collect ----
  int i = blockIdx.x * 256 + t;
  int stride = gridDim.x * 256;
  for (; i < n; i += stride) {
    uint32_t key = fkey(scores[i]);
    if ((key >> 16) >= T) {
      int pos = atomicAdd(cnt, 1);
      if (pos < CAP) {
        cand[pos] = ((unsigned long long)key << 32) | (uint32_t)(~(uint32_t)i);
      }
    }
  }
}

// Kernel F: rank candidates (distinct keys -> exact ranks), emit idx (as f32)
// and gather the TOPK rows. 1024 threads: 16 waves x 4 rows for the gather.
__global__ __launch_bounds__(1024) void final_kernel(
    const unsigned long long* __restrict__ cand, const int* __restrict__ cnt,
    const float* __restrict__ mat, float* __restrict__ out) {
  __shared__ unsigned long long c[CAP];
  __shared__ int sel[TOPK];
  int t = threadIdx.x;
  int M = *cnt;
  if (M > CAP) M = CAP;

  for (int i = t; i < M; i += 1024) c[i] = cand[i];
  __syncthreads();

  for (int i = t; i < M; i += 1024) {
    unsigned long long mykey = c[i];
    int rank = 0;
    for (int j = 0; j < M; ++j) rank += (c[j] > mykey) ? 1 : 0;
    if (rank < TOPK) sel[rank] = (int)(~(uint32_t)(mykey & 0xFFFFFFFFull));
  }
  __syncthreads();

  // idx output, written as float32 values
  if (t < TOPK) out[TOPK * DIM + t] = (float)sel[t];

  // gather rows: wave w handles rows w, w+16, ... ; lane l copies float4 block
  int wv = t >> 6, lane = t & 63;
  for (int r = wv; r < TOPK; r += 16) {
    size_t row = (size_t)sel[r];
    float4 v = ((const float4*)(mat + row * DIM))[lane];
    ((float4*)(out + r * DIM))[lane] = v;
  }
}

extern "C" void kernel_launch(void* const* d_in, const int* in_sizes, int n_in,
                              void* d_out, int out_size, void* d_ws, size_t ws_size,
                              hipStream_t stream) {
  const float* query = (const float*)d_in[0];
  const float* mat = (const float*)d_in[1];
  float* out = (float*)d_out;
  int n = in_sizes[1] / DIM;

  char* ws = (char*)d_ws;
  float* scores = (float*)ws;                               // n floats (<2 MB)
  uint32_t* hist = (uint32_t*)(ws + (2u << 20));            // 256 KB
  int* tbin = (int*)(ws + (2u << 20) + HIST_BINS * 4);
  int* cnt = tbin + 1;
  unsigned long long* cand =
      (unsigned long long*)(ws + (2u << 20) + HIST_BINS * 4 + 16);  // CAP*8

  // Grid sizing so every wave runs the same iteration count:
  // iters = ceil(n8 / (2048*4)); blocks = ceil(n8 / (4*iters)).
  int n8 = (n + 7) >> 3;
  int iters = (n8 + 8191) / 8192;
  int sblocks = (n8 + 4 * iters - 1) / (4 * iters);

  zero_kernel<<<64, 256, 0, stream>>>(hist, cnt);
  score_kernel<<<sblocks, 256, 0, stream>>>(mat, query, scores, hist, n);
  collect_kernel<<<512, 256, 0, stream>>>(scores, hist, cnt, cand, n);
  final_kernel<<<1, 1024, 0, stream>>>(cand, cnt, mat, out);
}